// Round 3
// baseline (20642.188 us; speedup 1.0000x reference)
//
#include <hip/hip_runtime.h>
#include <math.h>

// Problem dims
#define SLEN 256
#define BSZ  128
#define DIN  128
#define HSZ  512
#define HH2  1024
#define GG3  1536
#define OSZ  25
#define NWG  128

typedef _Float16 h8 __attribute__((ext_vector_type(8)));
typedef float    f4 __attribute__((ext_vector_type(4)));

struct P_t {
  const float *x, *noise, *b_cin, *b1, *b2, *b3, *w4, *b4, *b_ih, *b_hh, *w_out, *b_out;
  _Float16 *WT1, *WT2, *WT3, *WTih, *WThh, *WTcin;   // row-major [N][K] (setup)
  _Float16 *FW1, *FW2, *FW3, *FWih, *FWhh;           // fragment-major (hot path)
  _Float16 *CIN, *COMlo, *Z1, *Z2, *HF16;
  float *LOGI, *GX, *PART, *HGRU;
  float *CF[2], *HF[2], *NF[2];                      // ping-pong state
  int   *BAR;
  float *out;
};

__device__ __forceinline__ f4 mfma16(h8 a, h8 b, f4 c) {
  return __builtin_amdgcn_mfma_f32_16x16x32_f16(a, b, c, 0, 0, 0);
}

// ---- fence-free coherent accessors (relaxed agent atomics -> sc-flagged, L2-bypass,
// served by the chip-coherent L3; same mechanism as the barrier flags, HW-proven) ----
__device__ __forceinline__ float ldc_f(const float* p) {
  return __hip_atomic_load(p, __ATOMIC_RELAXED, __HIP_MEMORY_SCOPE_AGENT);
}
__device__ __forceinline__ void stc_f(float* p, float v) {
  __hip_atomic_store(p, v, __ATOMIC_RELAXED, __HIP_MEMORY_SCOPE_AGENT);
}
__device__ __forceinline__ int ldc_i(const int* p) {
  return __hip_atomic_load(p, __ATOMIC_RELAXED, __HIP_MEMORY_SCOPE_AGENT);
}
__device__ __forceinline__ void stc_i(int* p, int v) {
  __hip_atomic_store(p, v, __ATOMIC_RELAXED, __HIP_MEMORY_SCOPE_AGENT);
}
__device__ __forceinline__ void stc_u(unsigned* p, unsigned v) {
  __hip_atomic_store(p, v, __ATOMIC_RELAXED, __HIP_MEMORY_SCOPE_AGENT);
}
__device__ __forceinline__ h8 ldc_h8(const _Float16* p) {
  const unsigned* ip = (const unsigned*)p;
  union { unsigned u[4]; h8 v; } r;
  r.u[0] = __hip_atomic_load(ip + 0, __ATOMIC_RELAXED, __HIP_MEMORY_SCOPE_AGENT);
  r.u[1] = __hip_atomic_load(ip + 1, __ATOMIC_RELAXED, __HIP_MEMORY_SCOPE_AGENT);
  r.u[2] = __hip_atomic_load(ip + 2, __ATOMIC_RELAXED, __HIP_MEMORY_SCOPE_AGENT);
  r.u[3] = __hip_atomic_load(ip + 3, __ATOMIC_RELAXED, __HIP_MEMORY_SCOPE_AGENT);
  return r.v;
}
__device__ __forceinline__ unsigned pk16(float a, float b) {
  _Float16 ha = (_Float16)a, hb = (_Float16)b;
  unsigned short ua = __builtin_bit_cast(unsigned short, ha);
  unsigned short ub = __builtin_bit_cast(unsigned short, hb);
  return (unsigned)ua | ((unsigned)ub << 16);
}

// Fence-free flag-gather barrier. All mutable data travels on the coherent
// (sc-flagged) path, so no buffer_inv/wbl2 is needed: L2-cached weights stay hot.
__device__ __forceinline__ void gbar(int* bar, int epoch) {
  asm volatile("s_waitcnt vmcnt(0)" ::: "memory");   // my wave's coh-stores drained
  __syncthreads();                                   // whole WG drained
  const int tid = threadIdx.x;
  if (blockIdx.x == 0) {
    if (tid < 64) {
      const int i0 = 1 + tid;          // flags 1..64
      const int i1 = 65 + tid;         // flags 65..127
      const bool has1 = (i1 < NWG);
      for (;;) {
        int f0 = ldc_i(bar + (size_t)i0 * 16);
        int f1 = has1 ? ldc_i(bar + (size_t)i1 * 16) : epoch;
        if (__all(f0 >= epoch && f1 >= epoch)) break;
        __builtin_amdgcn_s_sleep(1);
      }
      if (tid == 0) stc_i(bar, epoch);
    }
  } else {
    if (tid == 0) {
      stc_i(bar + (size_t)blockIdx.x * 16, epoch);
      while (ldc_i(bar) < epoch) __builtin_amdgcn_s_sleep(1);
    }
  }
  __syncthreads();
  asm volatile("" ::: "memory");
}

// ---------------- setup kernels (unchanged) ----------------
__global__ __launch_bounds__(256) void transpose_cvt(const float* __restrict__ src,
    _Float16* __restrict__ dst, int K, int N) {
  __shared__ float tl[32][33];
  int nt = N >> 5;
  int bx = blockIdx.x % nt, by = blockIdx.x / nt;
  int n0 = bx << 5, k0 = by << 5;
  int tx = threadIdx.x & 31, ty = threadIdx.x >> 5;
#pragma unroll
  for (int i = 0; i < 4; ++i) {
    int r = ty + (i << 3);
    tl[r][tx] = src[(size_t)(k0 + r) * N + n0 + tx];
  }
  __syncthreads();
#pragma unroll
  for (int i = 0; i < 4; ++i) {
    int r = ty + (i << 3);
    dst[(size_t)(n0 + r) * K + k0 + tx] = (_Float16)tl[tx][r];
  }
}

__global__ __launch_bounds__(512) void fragpack(const _Float16* __restrict__ src,
    _Float16* __restrict__ dst, int K) {
  int ct = blockIdx.x;
  int chunks = (K / 32) * 64;
  for (int idx = threadIdx.x; idx < chunks; idx += 512) {
    int i = idx >> 6, lane = idx & 63;
    int mlw = lane & 15, qw = lane >> 4;
    *(h8*)(dst + ((size_t)ct * (K / 32) + i) * 512 + (size_t)lane * 8) =
        *(const h8*)(src + ((size_t)ct * 16 + mlw) * K + i * 32 + qw * 8);
  }
}

__global__ __launch_bounds__(256) void cin_kernel(P_t P) {
  int tid = blockIdx.x * blockDim.x + threadIdx.x;
  if (tid < SLEN * BSZ) {
    float u = P.noise[tid];
    P.LOGI[tid] = logf(u) - log1pf(-u);
  }
  int gw = tid >> 6, lane = tid & 63;
  int nw = (gridDim.x * blockDim.x) >> 6;
  int ml = lane & 15, q = lane >> 4;
  const int MT = (SLEN * BSZ) / 16;
  for (int tt = gw; tt < MT * 8; tt += nw) {
    int mt = tt & (MT - 1), nt = tt / MT;
    int m0 = mt * 16, n0 = nt * 64;
    int m = m0 + ml, b = m & 127, s = m >> 7;
    const float* ap = P.x + ((size_t)b * SLEN + s) * DIN + q * 8;
    const _Float16* bp = P.WTcin + (size_t)(n0 + ml) * DIN + q * 8;
    f4 a0 = {0,0,0,0}, a1 = a0, a2 = a0, a3 = a0;
#pragma unroll
    for (int k = 0; k < DIN; k += 32) {
      f4 lo = *(const f4*)(ap + k);
      f4 hi = *(const f4*)(ap + k + 4);
      h8 av;
      av[0] = (_Float16)lo[0]; av[1] = (_Float16)lo[1];
      av[2] = (_Float16)lo[2]; av[3] = (_Float16)lo[3];
      av[4] = (_Float16)hi[0]; av[5] = (_Float16)hi[1];
      av[6] = (_Float16)hi[2]; av[7] = (_Float16)hi[3];
      a0 = mfma16(av, *(const h8*)(bp + k),            a0);
      a1 = mfma16(av, *(const h8*)(bp + 16*DIN + k),   a1);
      a2 = mfma16(av, *(const h8*)(bp + 32*DIN + k),   a2);
      a3 = mfma16(av, *(const h8*)(bp + 48*DIN + k),   a3);
    }
#pragma unroll
    for (int r = 0; r < 4; ++r) {
      int row = m0 + q * 4 + r;
      int c0 = n0 + ml;
      P.CIN[(size_t)row * HSZ + c0     ] = (_Float16)tanhf(a0[r] + P.b_cin[c0]);
      P.CIN[(size_t)row * HSZ + c0 + 16] = (_Float16)tanhf(a1[r] + P.b_cin[c0 + 16]);
      P.CIN[(size_t)row * HSZ + c0 + 32] = (_Float16)tanhf(a2[r] + P.b_cin[c0 + 32]);
      P.CIN[(size_t)row * HSZ + c0 + 48] = (_Float16)tanhf(a3[r] + P.b_cin[c0 + 48]);
    }
  }
}

__global__ __launch_bounds__(256) void init_kernel(P_t P) {
  int idx = blockIdx.x * 256 + threadIdx.x;
  if (idx < BSZ * HSZ) {
    P.CF[0][idx] = 0.f; P.CF[1][idx] = 0.f;
    P.HF[0][idx] = 0.f; P.HF[1][idx] = 0.f;
    P.HF16[idx] = (_Float16)0.f; P.COMlo[idx] = (_Float16)0.f;
  }
  if (idx < BSZ) { P.NF[0][idx] = 0.f; P.NF[1][idx] = 0.f; }
  if (idx < 2048) P.BAR[idx] = 0;
}

// ---------------- persistent time-loop kernel ----------------
// 128 WGs x 256 thr. Per step: 3 fence-free device barriers.
// Mutable tensors: coherent (sc) path. Weights/CIN/LOGI: normal cached path (L2-hot).
__global__ __launch_bounds__(256) void loop_kernel(P_t P) {
  const int tid  = threadIdx.x;
  const int lane = tid & 63, wv = tid >> 6;
  const int ml   = lane & 15, q = lane >> 4;
  const int b    = blockIdx.x;
  const int gw   = b * 4 + wv;
  const int rt   = b >> 4, cg = b & 15;   // stage-A mapping: 8 row-blocks x 16 col-groups
  const int m0   = rt << 4;

  __shared__ _Float16 c_lds[16][520];
  __shared__ float sA[16], sNOM[16], sNN[16];

  int ep = 0;

#pragma unroll 1
  for (int it = 0; it < SLEN; ++it) {
    // ---------------- Stage A ----------------
    if (it == 0) {
      for (int e = tid; e < 16 * 512; e += 256) c_lds[e >> 9][e & 511] = (_Float16)0.f;
    } else {
      const int s = it - 1;
      const float* CFo = P.CF[(s + 1) & 1];
      const float* HFo = P.HF[(s + 1) & 1];
      const float* NFo = P.NF[(s + 1) & 1];
      float* CFn = P.CF[s & 1];
      float* HFn = P.HF[s & 1];
      float* NFn = P.NF[s & 1];
      {
        int rl = tid >> 4, sg = tid & 15;
        int row = m0 + rl;
        float v = ldc_f(&P.PART[(size_t)(sg * 4 + 0) * BSZ + row])
                + ldc_f(&P.PART[(size_t)(sg * 4 + 1) * BSZ + row])
                + ldc_f(&P.PART[(size_t)(sg * 4 + 2) * BSZ + row])
                + ldc_f(&P.PART[(size_t)(sg * 4 + 3) * BSZ + row]);
        v += __shfl_xor(v, 1); v += __shfl_xor(v, 2);
        v += __shfl_xor(v, 4); v += __shfl_xor(v, 8);
        if (sg == 0) {
          float lg = (v + P.b4[0] + P.LOGI[(size_t)s * BSZ + row]) * 10.0f;
          float al = 1.f / (1.f + expf(-lg));
          float om = 1.f - al;
          float no = ldc_f(&NFo[row]);
          float nn = no * om + 1.f;
          sA[rl] = al; sNOM[rl] = no * om; sNN[rl] = nn;
          if (cg == 0) stc_f(&NFn[row], nn);
        }
      }
      __syncthreads();
      // two adjacent cols per thread -> 4B packed coherent stores
      for (int e = tid * 2; e < 16 * 512; e += 512) {
        int rl = e >> 9, col = e & 511;
        int row = m0 + rl;
        float al = sA[rl], nom = sNOM[rl], nn = sNN[rl];
        size_t go = (size_t)row * HSZ + col;
        float hg0 = ldc_f(&P.HGRU[go]),  hg1 = ldc_f(&P.HGRU[go + 1]);
        float ho0 = ldc_f(&HFo[go]),     ho1 = ldc_f(&HFo[go + 1]);
        float co0 = ldc_f(&CFo[go]),     co1 = ldc_f(&CFo[go + 1]);
        size_t ci = ((size_t)s * BSZ + row) * HSZ + col;
        float ci0 = (float)P.CIN[ci], ci1 = (float)P.CIN[ci + 1];
        float hn0 = ho0 * (1.f - al) + al * hg0;
        float hn1 = ho1 * (1.f - al) + al * hg1;
        float cn0 = (co0 * nom + ci0) / nn;
        float cn1 = (co1 * nom + ci1) / nn;
        c_lds[rl][col] = (_Float16)cn0;
        c_lds[rl][col + 1] = (_Float16)cn1;
        if (cg == 0) {
          stc_f(&CFn[go], cn0); stc_f(&CFn[go + 1], cn1);
          stc_f(&HFn[go], hn0); stc_f(&HFn[go + 1], hn1);
          stc_u((unsigned*)&P.COMlo[go], pk16(cn0, cn1));
          stc_u((unsigned*)&P.HF16[go],  pk16(hn0, hn1));
        }
      }
    }
    __syncthreads();
    // z1 tile (rt, ct = cg*4+wv): K = [c (LDS) | cin (global, read-only cached)]
    {
      int ct  = (cg << 2) + wv;
      int col = (ct << 4) + ml;
      const _Float16* a1 = P.CIN + ((size_t)it * BSZ + m0 + ml) * HSZ + q * 8;
      const _Float16* bp = P.FW1 + (size_t)ct * 32 * 512 + (size_t)lane * 8;
      const _Float16* a0 = &c_lds[ml][q * 8];
      f4 acc = {0.f, 0.f, 0.f, 0.f};
#pragma unroll
      for (int k = 0; k < 16; ++k)
        acc = mfma16(*(const h8*)(a0 + k * 32), *(const h8*)(bp + (size_t)k * 512), acc);
#pragma unroll
      for (int k = 0; k < 16; ++k)
        acc = mfma16(*(const h8*)(a1 + k * 32), *(const h8*)(bp + (size_t)(16 + k) * 512), acc);
      float bia = P.b1[col];
#pragma unroll
      for (int j = 0; j < 4; ++j) {
        _Float16 hv = (_Float16)fmaxf(acc[j] + bia, 0.f);
        unsigned short mb = __builtin_bit_cast(unsigned short, hv);
        unsigned ob = (unsigned)__shfl_xor((int)mb, 1) & 0xffffu;
        if (!(ml & 1))
          stc_u((unsigned*)&P.Z1[(size_t)(m0 + q * 4 + j) * HH2 + col],
                (unsigned)mb | (ob << 16));
      }
    }
    gbar(P.BAR, ++ep);

    // ---------------- Stage B: z2 + gx ----------------
    for (int item = gw; item < 1280; item += 512) {
      if (item < 512) {
        int ct2 = item & 63, rt2 = item >> 6;
        int m2 = rt2 << 4, col = (ct2 << 4) + ml;
        const _Float16* a0 = P.Z1 + (size_t)(m2 + ml) * HH2 + q * 8;
        const _Float16* bp = P.FW2 + (size_t)ct2 * 32 * 512 + (size_t)lane * 8;
        f4 acc = {0.f, 0.f, 0.f, 0.f};
#pragma unroll
        for (int k = 0; k < 32; ++k)
          acc = mfma16(ldc_h8(a0 + k * 32), *(const h8*)(bp + (size_t)k * 512), acc);
        float bia = P.b2[col];
#pragma unroll
        for (int j = 0; j < 4; ++j) {
          _Float16 hv = (_Float16)fmaxf(acc[j] + bia, 0.f);
          unsigned short mb = __builtin_bit_cast(unsigned short, hv);
          unsigned ob = (unsigned)__shfl_xor((int)mb, 1) & 0xffffu;
          if (!(ml & 1))
            stc_u((unsigned*)&P.Z2[(size_t)(m2 + q * 4 + j) * HH2 + col],
                  (unsigned)mb | (ob << 16));
        }
      } else {
        int u = item - 512;
        int ct2 = u % 96, rt2 = u / 96;
        int m2 = rt2 << 4, col = (ct2 << 4) + ml;
        const _Float16* a0 = P.COMlo + (size_t)(m2 + ml) * HSZ + q * 8;
        const _Float16* bp = P.FWih + (size_t)ct2 * 16 * 512 + (size_t)lane * 8;
        f4 acc = {0.f, 0.f, 0.f, 0.f};
#pragma unroll
        for (int k = 0; k < 16; ++k)
          acc = mfma16(ldc_h8(a0 + k * 32), *(const h8*)(bp + (size_t)k * 512), acc);
        float bia = P.b_ih[col];
#pragma unroll
        for (int j = 0; j < 4; ++j)
          stc_f(&P.GX[(size_t)(m2 + q * 4 + j) * GG3 + col], acc[j] + bia);
      }
    }
    gbar(P.BAR, ++ep);

    // ---------------- Stage C: z3->PART + gh (fused GRU gates) -> HGRU ----------------
    {
      const float* HFo = P.HF[(it + 1) & 1];   // h(it-1)
      for (int item = gw; item < 768; item += 512) {
        if (item < 512) {
          int ct3 = item & 63, rt3 = item >> 6;
          int m3 = rt3 << 4, col = (ct3 << 4) + ml;
          const _Float16* a0 = P.Z2 + (size_t)(m3 + ml) * HH2 + q * 8;
          const _Float16* bp = P.FW3 + (size_t)ct3 * 32 * 512 + (size_t)lane * 8;
          f4 acc = {0.f, 0.f, 0.f, 0.f};
#pragma unroll
          for (int k = 0; k < 32; ++k)
            acc = mfma16(ldc_h8(a0 + k * 32), *(const h8*)(bp + (size_t)k * 512), acc);
          float bia = P.b3[col], w4v = P.w4[col];
#pragma unroll
          for (int j = 0; j < 4; ++j) {
            float v = fmaxf(acc[j] + bia, 0.f) * w4v;
            v += __shfl_xor(v, 1); v += __shfl_xor(v, 2);
            v += __shfl_xor(v, 4); v += __shfl_xor(v, 8);
            if (ml == 0) stc_f(&P.PART[(size_t)ct3 * BSZ + m3 + q * 4 + j], v);
          }
        } else {
          int u = item - 512;                     // 0..255
          int tc = u & 31, rt3 = u >> 5;
          int m3 = rt3 << 4, colr = (tc << 4) + ml;
          const _Float16* a0  = P.HF16 + (size_t)(m3 + ml) * HSZ + q * 8;
          const _Float16* bpr = P.FWhh + (size_t)tc * 16 * 512 + (size_t)lane * 8;
          const _Float16* bpz = P.FWhh + (size_t)(tc + 32) * 16 * 512 + (size_t)lane * 8;
          const _Float16* bpn = P.FWhh + (size_t)(tc + 64) * 16 * 512 + (size_t)lane * 8;
          f4 ar = {0.f, 0.f, 0.f, 0.f}, az = ar, an = ar;
#pragma unroll
          for (int k = 0; k < 16; ++k) {
            h8 av = ldc_h8(a0 + k * 32);
            ar = mfma16(av, *(const h8*)(bpr + (size_t)k * 512), ar);
            az = mfma16(av, *(const h8*)(bpz + (size_t)k * 512), az);
            an = mfma16(av, *(const h8*)(bpn + (size_t)k * 512), an);
          }
          float bhr = P.b_hh[colr], bhz = P.b_hh[colr + 512], bhn = P.b_hh[colr + 1024];
#pragma unroll
          for (int j = 0; j < 4; ++j) {
            int row = m3 + q * 4 + j;
            size_t g3 = (size_t)row * GG3 + colr;
            float xr = ldc_f(&P.GX[g3]);
            float xz = ldc_f(&P.GX[g3 + 512]);
            float xn = ldc_f(&P.GX[g3 + 1024]);
            float rg = 1.f / (1.f + expf(-(xr + ar[j] + bhr)));
            float zg = 1.f / (1.f + expf(-(xz + az[j] + bhz)));
            float ng = tanhf(xn + rg * (an[j] + bhn));
            float ho = ldc_f(&HFo[(size_t)row * HSZ + colr]);
            stc_f(&P.HGRU[(size_t)row * HSZ + colr], (1.f - zg) * ng + zg * ho);
          }
        }
      }
    }
    gbar(P.BAR, ++ep);
  }

  // ---------------- Epilogue ----------------
  // E1: update(255) -> c(255) f16 (COMlo), h(255) f16/f32
  {
    const int s = SLEN - 1;
    const float* CFo = P.CF[(s + 1) & 1];
    const float* HFo = P.HF[(s + 1) & 1];
    const float* NFo = P.NF[(s + 1) & 1];
    float* HFn = P.HF[s & 1];
    {
      int rl = tid >> 4, sg = tid & 15;
      int row = m0 + rl;
      float v = ldc_f(&P.PART[(size_t)(sg * 4 + 0) * BSZ + row])
              + ldc_f(&P.PART[(size_t)(sg * 4 + 1) * BSZ + row])
              + ldc_f(&P.PART[(size_t)(sg * 4 + 2) * BSZ + row])
              + ldc_f(&P.PART[(size_t)(sg * 4 + 3) * BSZ + row]);
      v += __shfl_xor(v, 1); v += __shfl_xor(v, 2);
      v += __shfl_xor(v, 4); v += __shfl_xor(v, 8);
      if (sg == 0) {
        float lg = (v + P.b4[0] + P.LOGI[(size_t)s * BSZ + row]) * 10.0f;
        float al = 1.f / (1.f + expf(-lg));
        float om = 1.f - al;
        float no = ldc_f(&NFo[row]);
        sA[rl] = al; sNOM[rl] = no * om; sNN[rl] = no * om + 1.f;
      }
    }
    __syncthreads();
    if (cg == 0) {
      for (int e = tid * 2; e < 16 * 512; e += 512) {
        int rl = e >> 9, col = e & 511;
        int row = m0 + rl;
        size_t go = (size_t)row * HSZ + col;
        float al = sA[rl];
        float hn0 = ldc_f(&HFo[go]) * (1.f - al) + al * ldc_f(&P.HGRU[go]);
        float hn1 = ldc_f(&HFo[go + 1]) * (1.f - al) + al * ldc_f(&P.HGRU[go + 1]);
        size_t ci = ((size_t)s * BSZ + row) * HSZ + col;
        float cn0 = (ldc_f(&CFo[go]) * sNOM[rl] + (float)P.CIN[ci]) / sNN[rl];
        float cn1 = (ldc_f(&CFo[go + 1]) * sNOM[rl] + (float)P.CIN[ci + 1]) / sNN[rl];
        stc_f(&HFn[go], hn0); stc_f(&HFn[go + 1], hn1);
        stc_u((unsigned*)&P.HF16[go],  pk16(hn0, hn1));
        stc_u((unsigned*)&P.COMlo[go], pk16(cn0, cn1));
      }
    }
  }
  gbar(P.BAR, ++ep);

  // E2: GX = c(255) @ W_ih + b_ih
  for (int item = gw; item < 768; item += 512) {
    int ct2 = item % 96, rt2 = item / 96;
    int m2 = rt2 << 4, col = (ct2 << 4) + ml;
    const _Float16* a0 = P.COMlo + (size_t)(m2 + ml) * HSZ + q * 8;
    const _Float16* bp = P.FWih + (size_t)ct2 * 16 * 512 + (size_t)lane * 8;
    f4 acc = {0.f, 0.f, 0.f, 0.f};
#pragma unroll
    for (int k = 0; k < 16; ++k)
      acc = mfma16(ldc_h8(a0 + k * 32), *(const h8*)(bp + (size_t)k * 512), acc);
    float bia = P.b_ih[col];
#pragma unroll
    for (int j = 0; j < 4; ++j)
      stc_f(&P.GX[(size_t)(m2 + q * 4 + j) * GG3 + col], acc[j] + bia);
  }
  gbar(P.BAR, ++ep);

  // E3: gh triples -> h_fin into HGRU
  {
    const float* HFo = P.HF[(SLEN - 1) & 1];   // h(255)
    for (int item = gw; item < 256; item += 512) {
      int tc = item & 31, rt3 = item >> 5;
      int m3 = rt3 << 4, colr = (tc << 4) + ml;
      const _Float16* a0  = P.HF16 + (size_t)(m3 + ml) * HSZ + q * 8;
      const _Float16* bpr = P.FWhh + (size_t)tc * 16 * 512 + (size_t)lane * 8;
      const _Float16* bpz = P.FWhh + (size_t)(tc + 32) * 16 * 512 + (size_t)lane * 8;
      const _Float16* bpn = P.FWhh + (size_t)(tc + 64) * 16 * 512 + (size_t)lane * 8;
      f4 ar = {0.f, 0.f, 0.f, 0.f}, az = ar, an = ar;
#pragma unroll
      for (int k = 0; k < 16; ++k) {
        h8 av = ldc_h8(a0 + k * 32);
        ar = mfma16(av, *(const h8*)(bpr + (size_t)k * 512), ar);
        az = mfma16(av, *(const h8*)(bpz + (size_t)k * 512), az);
        an = mfma16(av, *(const h8*)(bpn + (size_t)k * 512), an);
      }
      float bhr = P.b_hh[colr], bhz = P.b_hh[colr + 512], bhn = P.b_hh[colr + 1024];
#pragma unroll
      for (int j = 0; j < 4; ++j) {
        int row = m3 + q * 4 + j;
        size_t g3 = (size_t)row * GG3 + colr;
        float xr = ldc_f(&P.GX[g3]);
        float xz = ldc_f(&P.GX[g3 + 512]);
        float xn = ldc_f(&P.GX[g3 + 1024]);
        float rg = 1.f / (1.f + expf(-(xr + ar[j] + bhr)));
        float zg = 1.f / (1.f + expf(-(xz + az[j] + bhz)));
        float ng = tanhf(xn + rg * (an[j] + bhn));
        float ho = ldc_f(&HFo[(size_t)row * HSZ + colr]);
        stc_f(&P.HGRU[(size_t)row * HSZ + colr], (1.f - zg) * ng + zg * ho);
      }
    }
  }
  gbar(P.BAR, ++ep);

  // E4: out[row b] = h_fin @ w_out + b_out
  {
    __shared__ float hfl[512];
    const float* hsrc = P.HGRU + (size_t)b * HSZ;
    for (int e = tid; e < 512; e += 256) hfl[e] = ldc_f(&hsrc[e]);
    __syncthreads();
    for (int c2 = wv; c2 < OSZ; c2 += 4) {
      float v = 0.f;
#pragma unroll
      for (int j = 0; j < 8; ++j)
        v += hfl[lane + 64 * j] * P.w_out[(size_t)(lane + 64 * j) * OSZ + c2];
      for (int off = 32; off > 0; off >>= 1) v += __shfl_xor(v, off);
      if (lane == 0) P.out[b * OSZ + c2] = v + P.b_out[c2];
    }
  }
}

// ---------------- host ----------------
extern "C" void kernel_launch(void* const* d_in, const int* in_sizes, int n_in,
                              void* d_out, int out_size, void* d_ws, size_t ws_size,
                              hipStream_t stream) {
  const float* x     = (const float*)d_in[0];
  const float* noise = (const float*)d_in[1];
  const float* w_cin = (const float*)d_in[2];
  const float* b_cin = (const float*)d_in[3];
  const float* w1    = (const float*)d_in[4];
  const float* b1    = (const float*)d_in[5];
  const float* w2    = (const float*)d_in[6];
  const float* b2    = (const float*)d_in[7];
  const float* w3    = (const float*)d_in[8];
  const float* b3    = (const float*)d_in[9];
  const float* w4    = (const float*)d_in[10];
  const float* b4    = (const float*)d_in[11];
  const float* w_ih  = (const float*)d_in[12];
  const float* b_ih  = (const float*)d_in[13];
  const float* w_hh  = (const float*)d_in[14];
  const float* b_hh  = (const float*)d_in[15];
  const float* w_out = (const float*)d_in[16];
  const float* b_out = (const float*)d_in[17];

  char* ws = (char*)d_ws;
  size_t off = 0;
  auto alloc = [&](size_t bytes) -> void* {
    void* p = ws + off;
    off = (off + bytes + 255) & ~(size_t)255;
    return p;
  };

  P_t P;
  P.x = x; P.noise = noise; P.b_cin = b_cin; P.b1 = b1; P.b2 = b2; P.b3 = b3;
  P.w4 = w4; P.b4 = b4; P.b_ih = b_ih; P.b_hh = b_hh; P.w_out = w_out; P.b_out = b_out;
  P.WT1   = (_Float16*)alloc((size_t)HH2 * HH2 * 2);
  P.WT2   = (_Float16*)alloc((size_t)HH2 * HH2 * 2);
  P.WT3   = (_Float16*)alloc((size_t)HH2 * HH2 * 2);
  P.WTih  = (_Float16*)alloc((size_t)GG3 * HSZ * 2);
  P.WThh  = (_Float16*)alloc((size_t)GG3 * HSZ * 2);
  P.WTcin = (_Float16*)alloc((size_t)HSZ * DIN * 2);
  P.FW1   = (_Float16*)alloc((size_t)HH2 * HH2 * 2);
  P.FW2   = (_Float16*)alloc((size_t)HH2 * HH2 * 2);
  P.FW3   = (_Float16*)alloc((size_t)HH2 * HH2 * 2);
  P.FWih  = (_Float16*)alloc((size_t)GG3 * HSZ * 2);
  P.FWhh  = (_Float16*)alloc((size_t)GG3 * HSZ * 2);
  P.CIN   = (_Float16*)alloc((size_t)SLEN * BSZ * HSZ * 2);
  P.COMlo = (_Float16*)alloc((size_t)BSZ * HSZ * 2);
  P.Z1    = (_Float16*)alloc((size_t)BSZ * HH2 * 2);
  P.Z2    = (_Float16*)alloc((size_t)BSZ * HH2 * 2);
  P.HF16  = (_Float16*)alloc((size_t)BSZ * HSZ * 2);
  P.LOGI  = (float*)alloc((size_t)SLEN * BSZ * 4);
  P.GX    = (float*)alloc((size_t)BSZ * GG3 * 4);
  P.PART  = (float*)alloc((size_t)64 * BSZ * 4);
  P.HGRU  = (float*)alloc((size_t)BSZ * HSZ * 4);
  P.CF[0] = (float*)alloc((size_t)BSZ * HSZ * 4);
  P.CF[1] = (float*)alloc((size_t)BSZ * HSZ * 4);
  P.HF[0] = (float*)alloc((size_t)BSZ * HSZ * 4);
  P.HF[1] = (float*)alloc((size_t)BSZ * HSZ * 4);
  P.NF[0] = (float*)alloc((size_t)BSZ * 4);
  P.NF[1] = (float*)alloc((size_t)BSZ * 4);
  P.BAR   = (int*)alloc(2048 * 4);
  P.out   = (float*)d_out;

  transpose_cvt<<<(HH2/32)*(HH2/32), 256, 0, stream>>>(w1, P.WT1, HH2, HH2);
  transpose_cvt<<<(HH2/32)*(HH2/32), 256, 0, stream>>>(w2, P.WT2, HH2, HH2);
  transpose_cvt<<<(HH2/32)*(HH2/32), 256, 0, stream>>>(w3, P.WT3, HH2, HH2);
  transpose_cvt<<<(GG3/32)*(HSZ/32), 256, 0, stream>>>(w_ih, P.WTih, HSZ, GG3);
  transpose_cvt<<<(GG3/32)*(HSZ/32), 256, 0, stream>>>(w_hh, P.WThh, HSZ, GG3);
  transpose_cvt<<<(HSZ/32)*(DIN/32), 256, 0, stream>>>(w_cin, P.WTcin, DIN, HSZ);
  fragpack<<<HH2/16, 512, 0, stream>>>(P.WT1, P.FW1, HH2);
  fragpack<<<HH2/16, 512, 0, stream>>>(P.WT2, P.FW2, HH2);
  fragpack<<<HH2/16, 512, 0, stream>>>(P.WT3, P.FW3, HH2);
  fragpack<<<GG3/16, 512, 0, stream>>>(P.WTih, P.FWih, HSZ);
  fragpack<<<GG3/16, 512, 0, stream>>>(P.WThh, P.FWhh, HSZ);

  cin_kernel<<<1024, 256, 0, stream>>>(P);
  init_kernel<<<256, 256, 0, stream>>>(P);

  loop_kernel<<<NWG, 256, 0, stream>>>(P);
}

// Round 6
// 7036.906 us; speedup vs baseline: 2.9334x; 2.9334x over previous
//
#include <hip/hip_runtime.h>
#include <math.h>

// Problem dims
#define SLEN 256
#define BSZ  128
#define DIN  128
#define HSZ  512
#define HH2  1024
#define GG3  1536
#define OSZ  25

typedef _Float16 h8 __attribute__((ext_vector_type(8)));
typedef _Float16 h4v __attribute__((ext_vector_type(4)));
typedef float    f4 __attribute__((ext_vector_type(4)));

struct P_t {
  const float *x, *noise, *b_cin, *b1, *b2, *b3, *w4, *b4, *b_ih, *b_hh, *w_out, *b_out;
  _Float16 *WT1, *WT2, *WT3, *WTih, *WThh, *WTcin;   // row-major [N][K] (setup)
  _Float16 *FW1, *FW2, *FW3, *FWih, *FWhh;           // fragment-major (hot path)
  _Float16 *CIN, *Z1, *Z2;
  float *LOGI, *GX, *GH, *PART, *HGRU;
  float *CF, *HF, *NF;       // parity ping-pong: state(s) lives at half (s&1)
  float *out;
};

__device__ __forceinline__ f4 mfma16(h8 a, h8 b, f4 c) {
  return __builtin_amdgcn_mfma_f32_16x16x32_f16(a, b, c, 0, 0, 0);
}

// ---------------- setup kernels (unchanged, proven) ----------------
__global__ __launch_bounds__(256) void transpose_cvt(const float* __restrict__ src,
    _Float16* __restrict__ dst, int K, int N) {
  __shared__ float tl[32][33];
  int nt = N >> 5;
  int bx = blockIdx.x % nt, by = blockIdx.x / nt;
  int n0 = bx << 5, k0 = by << 5;
  int tx = threadIdx.x & 31, ty = threadIdx.x >> 5;
#pragma unroll
  for (int i = 0; i < 4; ++i) {
    int r = ty + (i << 3);
    tl[r][tx] = src[(size_t)(k0 + r) * N + n0 + tx];
  }
  __syncthreads();
#pragma unroll
  for (int i = 0; i < 4; ++i) {
    int r = ty + (i << 3);
    dst[(size_t)(n0 + r) * K + k0 + tx] = (_Float16)tl[tx][r];
  }
}

__global__ __launch_bounds__(512) void fragpack(const _Float16* __restrict__ src,
    _Float16* __restrict__ dst, int K) {
  int ct = blockIdx.x;
  int chunks = (K / 32) * 64;
  for (int idx = threadIdx.x; idx < chunks; idx += 512) {
    int i = idx >> 6, lane = idx & 63;
    int mlw = lane & 15, qw = lane >> 4;
    *(h8*)(dst + ((size_t)ct * (K / 32) + i) * 512 + (size_t)lane * 8) =
        *(const h8*)(src + ((size_t)ct * 16 + mlw) * K + i * 32 + qw * 8);
  }
}

__global__ __launch_bounds__(256) void cin_kernel(P_t P) {
  int tid = blockIdx.x * blockDim.x + threadIdx.x;
  if (tid < SLEN * BSZ) {
    float u = P.noise[tid];
    P.LOGI[tid] = logf(u) - log1pf(-u);
  }
  int gw = tid >> 6, lane = tid & 63;
  int nw = (gridDim.x * blockDim.x) >> 6;
  int ml = lane & 15, q = lane >> 4;
  const int MT = (SLEN * BSZ) / 16;
  for (int tt = gw; tt < MT * 8; tt += nw) {
    int mt = tt & (MT - 1), nt = tt / MT;
    int m0 = mt * 16, n0 = nt * 64;
    int m = m0 + ml, b = m & 127, s = m >> 7;
    const float* ap = P.x + ((size_t)b * SLEN + s) * DIN + q * 8;
    const _Float16* bp = P.WTcin + (size_t)(n0 + ml) * DIN + q * 8;
    f4 a0 = {0,0,0,0}, a1 = a0, a2 = a0, a3 = a0;
#pragma unroll
    for (int k = 0; k < DIN; k += 32) {
      f4 lo = *(const f4*)(ap + k);
      f4 hi = *(const f4*)(ap + k + 4);
      h8 av;
      av[0] = (_Float16)lo[0]; av[1] = (_Float16)lo[1];
      av[2] = (_Float16)lo[2]; av[3] = (_Float16)lo[3];
      av[4] = (_Float16)hi[0]; av[5] = (_Float16)hi[1];
      av[6] = (_Float16)hi[2]; av[7] = (_Float16)hi[3];
      a0 = mfma16(av, *(const h8*)(bp + k),            a0);
      a1 = mfma16(av, *(const h8*)(bp + 16*DIN + k),   a1);
      a2 = mfma16(av, *(const h8*)(bp + 32*DIN + k),   a2);
      a3 = mfma16(av, *(const h8*)(bp + 48*DIN + k),   a3);
    }
#pragma unroll
    for (int r = 0; r < 4; ++r) {
      int row = m0 + q * 4 + r;
      int c0 = n0 + ml;
      P.CIN[(size_t)row * HSZ + c0     ] = (_Float16)tanhf(a0[r] + P.b_cin[c0]);
      P.CIN[(size_t)row * HSZ + c0 + 16] = (_Float16)tanhf(a1[r] + P.b_cin[c0 + 16]);
      P.CIN[(size_t)row * HSZ + c0 + 32] = (_Float16)tanhf(a2[r] + P.b_cin[c0 + 32]);
      P.CIN[(size_t)row * HSZ + c0 + 48] = (_Float16)tanhf(a3[r] + P.b_cin[c0 + 48]);
    }
  }
}

__global__ __launch_bounds__(256) void init_kernel(P_t P) {
  int idx = blockIdx.x * 256 + threadIdx.x;
  if (idx < 2 * BSZ * HSZ) { P.CF[idx] = 0.f; P.HF[idx] = 0.f; }
  if (idx < 2 * BSZ) P.NF[idx] = 0.f;
}

// ---------------- K1: update(it-1) recompute + z1(it) + gx(it) + gh(it) ----------------
// Grid 512 x 256. Block b: rt = b>>6 (row-block), bu = b&63. Wave-tile u = bu*4+wv:
//   u<64: z1 ct=u | u<160: gx ct=u-64 | else: gh ct=u-160.
// Each block recomputes state(it-1) for its 16 rows from {canonical state(it-2),
// HGRU(it-1), PART(it-1)->alpha, CIN(it-1)} -- all written >=1 launch earlier; the
// bu==0 block per rt also writes canonical state(it-1) (parity buffers). No sync
// primitives: stream order is the only dependency mechanism. ct-peers share b%8 ->
// same XCD class -> weight panels L2-reused 8x.
// it==SLEN: epilogue mode (state(255) + gx/gh only, no z1).
__global__ __launch_bounds__(256) void step_k1(P_t P, int it) {
  const int tid = threadIdx.x;
  const int lane = tid & 63, wv = tid >> 6;
  const int ml = lane & 15, q = lane >> 4;
  const int b = blockIdx.x;
  const int rt = b >> 6, bu = b & 63;
  const int m0 = rt << 4;

  __shared__ _Float16 sC[16][520];
  __shared__ _Float16 sH[16][520];
  __shared__ _Float16 sCIN[16][520];
  __shared__ float sAl[16], sNOM[16], sNN[16];

  if (it == 0) {
    for (int c4 = tid; c4 < 2048; c4 += 256) {
      int rl = c4 >> 7, cb = (c4 & 127) << 2;
      h4v z = {(_Float16)0.f, (_Float16)0.f, (_Float16)0.f, (_Float16)0.f};
      *(h4v*)&sC[rl][cb] = z;
      *(h4v*)&sH[rl][cb] = z;
    }
  } else {
    const int s = it - 1;
    const float* CFo = P.CF + (size_t)((s + 1) & 1) * BSZ * HSZ;  // c(s-1)
    const float* HFo = P.HF + (size_t)((s + 1) & 1) * BSZ * HSZ;  // h(s-1)
    const float* NFo = P.NF + ((s + 1) & 1) * BSZ;                // n(s-1)
    float* CFn = P.CF + (size_t)(s & 1) * BSZ * HSZ;
    float* HFn = P.HF + (size_t)(s & 1) * BSZ * HSZ;
    float* NFn = P.NF + (s & 1) * BSZ;
    {
      int rl = tid >> 4, sg = tid & 15;
      int row = m0 + rl;
      float v = P.PART[(size_t)(sg * 4 + 0) * BSZ + row]
              + P.PART[(size_t)(sg * 4 + 1) * BSZ + row]
              + P.PART[(size_t)(sg * 4 + 2) * BSZ + row]
              + P.PART[(size_t)(sg * 4 + 3) * BSZ + row];
      v += __shfl_xor(v, 1); v += __shfl_xor(v, 2);
      v += __shfl_xor(v, 4); v += __shfl_xor(v, 8);
      if (sg == 0) {
        float lg = (v + P.b4[0] + P.LOGI[(size_t)s * BSZ + row]) * 10.0f;
        float al = 1.f / (1.f + expf(-lg));
        float om = 1.f - al;
        float no = NFo[row];
        float nn = no * om + 1.f;
        sAl[rl] = al; sNOM[rl] = no * om; sNN[rl] = nn;
        if (bu == 0) NFn[row] = nn;
      }
    }
    __syncthreads();
    for (int c4 = tid; c4 < 2048; c4 += 256) {
      int rl = c4 >> 7, cb = (c4 & 127) << 2;
      int row = m0 + rl;
      size_t go = (size_t)row * HSZ + cb;
      f4 hg = *(const f4*)(P.HGRU + go);
      f4 ho = *(const f4*)(HFo + go);
      f4 co = *(const f4*)(CFo + go);
      h4v ci = *(const h4v*)(P.CIN + ((size_t)s * BSZ + row) * HSZ + cb);
      float al = sAl[rl], om = 1.f - al, nom = sNOM[rl], nn = sNN[rl];
      f4 hn, cn;
#pragma unroll
      for (int j = 0; j < 4; ++j) {
        hn[j] = ho[j] * om + al * hg[j];
        cn[j] = (co[j] * nom + (float)ci[j]) / nn;
      }
      h4v c16, h16;
#pragma unroll
      for (int j = 0; j < 4; ++j) { c16[j] = (_Float16)cn[j]; h16[j] = (_Float16)hn[j]; }
      *(h4v*)&sC[rl][cb] = c16;
      *(h4v*)&sH[rl][cb] = h16;
      if (bu == 0) {
        *(f4*)(CFn + go) = cn;
        *(f4*)(HFn + go) = hn;
      }
    }
  }
  if (bu < 16 && it < SLEN) {
    for (int c8 = tid; c8 < 1024; c8 += 256) {
      int rl = c8 >> 6, cb = (c8 & 63) << 3;
      *(h8*)&sCIN[rl][cb] =
          *(const h8*)(P.CIN + ((size_t)it * BSZ + m0 + rl) * HSZ + cb);
    }
  }
  __syncthreads();

  const int u = bu * 4 + wv;
  if (u < 64) {
    if (it < SLEN) {
      int ct = u, col = (ct << 4) + ml;
      const _Float16* bp = P.FW1 + (size_t)ct * 32 * 512 + (size_t)lane * 8;
      const _Float16* ac = &sC[ml][q * 8];
      const _Float16* ai = &sCIN[ml][q * 8];
      f4 acc = {0.f, 0.f, 0.f, 0.f};
#pragma unroll
      for (int k = 0; k < 16; ++k)
        acc = mfma16(*(const h8*)(ac + k * 32), *(const h8*)(bp + (size_t)k * 512), acc);
#pragma unroll
      for (int k = 0; k < 16; ++k)
        acc = mfma16(*(const h8*)(ai + k * 32), *(const h8*)(bp + (size_t)(16 + k) * 512), acc);
      float bia = P.b1[col];
#pragma unroll
      for (int j = 0; j < 4; ++j)
        P.Z1[(size_t)(m0 + q * 4 + j) * HH2 + col] = (_Float16)fmaxf(acc[j] + bia, 0.f);
    }
  } else if (u < 160) {
    int ct = u - 64, col = (ct << 4) + ml;
    const _Float16* bp = P.FWih + (size_t)ct * 16 * 512 + (size_t)lane * 8;
    const _Float16* a0 = &sC[ml][q * 8];
    f4 acc = {0.f, 0.f, 0.f, 0.f};
#pragma unroll
    for (int k = 0; k < 16; ++k)
      acc = mfma16(*(const h8*)(a0 + k * 32), *(const h8*)(bp + (size_t)k * 512), acc);
    float bia = P.b_ih[col];
#pragma unroll
    for (int j = 0; j < 4; ++j)
      P.GX[(size_t)(m0 + q * 4 + j) * GG3 + col] = acc[j] + bia;
  } else {
    int ct = u - 160, col = (ct << 4) + ml;
    const _Float16* bp = P.FWhh + (size_t)ct * 16 * 512 + (size_t)lane * 8;
    const _Float16* a0 = &sH[ml][q * 8];
    f4 acc = {0.f, 0.f, 0.f, 0.f};
#pragma unroll
    for (int k = 0; k < 16; ++k)
      acc = mfma16(*(const h8*)(a0 + k * 32), *(const h8*)(bp + (size_t)k * 512), acc);
    float bia = P.b_hh[col];
#pragma unroll
    for (int j = 0; j < 4; ++j)
      P.GH[(size_t)(m0 + q * 4 + j) * GG3 + col] = acc[j] + bia;
  }
}

// ---------------- K2: z2 = relu(z1@W2+b2) (baseline step_b, unchanged) ----------------
__global__ __launch_bounds__(256) void step_k2(P_t P) {
  const int tid = threadIdx.x;
  const int lane = tid & 63, wv = tid >> 6;
  const int ml = lane & 15, q = lane >> 4;
  const int g = blockIdx.x * 4 + wv;
  int rt = g & 7, ct = g >> 3;
  int m0 = rt * 16, col = ct * 16 + ml;
  const _Float16* a0 = P.Z1 + (size_t)(m0 + ml) * HH2 + q * 8;
  const _Float16* bp = P.FW2 + (size_t)ct * 32 * 512 + (size_t)lane * 8;
  f4 acc = {0.f, 0.f, 0.f, 0.f};
#pragma unroll
  for (int i = 0; i < 32; ++i)
    acc = mfma16(*(const h8*)(a0 + i * 32), *(const h8*)(bp + (size_t)i * 512), acc);
  float bia = P.b2[col];
#pragma unroll
  for (int j = 0; j < 4; ++j)
    P.Z2[(size_t)(m0 + q * 4 + j) * HH2 + col] = (_Float16)fmaxf(acc[j] + bia, 0.f);
}

// ---------------- K3: z3->PART + fused GRU gates -> HGRU(it) ----------------
__global__ __launch_bounds__(256) void step_k3(P_t P, int it) {
  const int tid = threadIdx.x;
  const int lane = tid & 63, wv = tid >> 6;
  const int ml = lane & 15, q = lane >> 4;
  const int g = blockIdx.x * 4 + wv;
  {
    int rt = g & 7, ct = g >> 3;
    int m0 = rt * 16, col = ct * 16 + ml;
    const _Float16* a0 = P.Z2 + (size_t)(m0 + ml) * HH2 + q * 8;
    const _Float16* bp = P.FW3 + (size_t)ct * 32 * 512 + (size_t)lane * 8;
    f4 acc = {0.f, 0.f, 0.f, 0.f};
#pragma unroll
    for (int i = 0; i < 32; ++i)
      acc = mfma16(*(const h8*)(a0 + i * 32), *(const h8*)(bp + (size_t)i * 512), acc);
    float bia = P.b3[col], w4v = P.w4[col];
#pragma unroll
    for (int j = 0; j < 4; ++j) {
      float v = fmaxf(acc[j] + bia, 0.f) * w4v;
      v += __shfl_xor(v, 1); v += __shfl_xor(v, 2);
      v += __shfl_xor(v, 4); v += __shfl_xor(v, 8);
      if (ml == 0) P.PART[(size_t)ct * BSZ + m0 + q * 4 + j] = v;
    }
  }
  // fused GRU gate nonlinearity: HGRU(it) = (1-z)*n + z*h(it-1); 512 elems/block
  {
    const float* HFo = P.HF + (size_t)((it + 1) & 1) * BSZ * HSZ;   // h(it-1)
    int e0 = blockIdx.x * 512;
#pragma unroll
    for (int ee = 0; ee < 2; ++ee) {
      int e = e0 + tid + ee * 256;
      int row = e >> 9, col = e & 511;
      size_t g3 = (size_t)row * GG3 + col;
      float xr = P.GX[g3], xz = P.GX[g3 + 512], xn = P.GX[g3 + 1024];
      float hr = P.GH[g3], hz = P.GH[g3 + 512], hn = P.GH[g3 + 1024];
      float rg = 1.f / (1.f + expf(-(xr + hr)));
      float zg = 1.f / (1.f + expf(-(xz + hz)));
      float ng = tanhf(xn + rg * hn);
      float ho = HFo[(size_t)row * HSZ + col];
      P.HGRU[(size_t)row * HSZ + col] = (1.f - zg) * ng + zg * ho;
    }
  }
}

// ---------------- final: h_fin = GRU gates(c255,h255) -> out ----------------
__global__ __launch_bounds__(512) void final_kernel(P_t P) {
  __shared__ float hf[512];
  const int r = blockIdx.x, tid = threadIdx.x;
  const int lane = tid & 63, wv = tid >> 6;
  const float* HFo = P.HF + (size_t)((SLEN - 1) & 1) * BSZ * HSZ;   // h(255)
  {
    int col = tid;
    size_t go = (size_t)r * GG3 + col;
    float xr = P.GX[go], xz = P.GX[go + 512], xn = P.GX[go + 1024];
    float hr = P.GH[go], hz = P.GH[go + 512], hn = P.GH[go + 1024];
    float rg = 1.f / (1.f + expf(-(xr + hr)));
    float zg = 1.f / (1.f + expf(-(xz + hz)));
    float ng = tanhf(xn + rg * hn);
    float h_old = HFo[(size_t)r * HSZ + col];
    hf[col] = (1.f - zg) * ng + zg * h_old;
  }
  __syncthreads();
  for (int c = wv; c < OSZ; c += 8) {
    float v = 0.f;
#pragma unroll
    for (int j = 0; j < 8; ++j)
      v += hf[lane + 64 * j] * P.w_out[(size_t)(lane + 64 * j) * OSZ + c];
#pragma unroll
    for (int off = 32; off > 0; off >>= 1) v += __shfl_xor(v, off);
    if (lane == 0) P.out[r * OSZ + c] = v + P.b_out[c];
  }
}

// ---------------- host ----------------
extern "C" void kernel_launch(void* const* d_in, const int* in_sizes, int n_in,
                              void* d_out, int out_size, void* d_ws, size_t ws_size,
                              hipStream_t stream) {
  const float* x     = (const float*)d_in[0];
  const float* noise = (const float*)d_in[1];
  const float* w_cin = (const float*)d_in[2];
  const float* b_cin = (const float*)d_in[3];
  const float* w1    = (const float*)d_in[4];
  const float* b1    = (const float*)d_in[5];
  const float* w2    = (const float*)d_in[6];
  const float* b2    = (const float*)d_in[7];
  const float* w3    = (const float*)d_in[8];
  const float* b3    = (const float*)d_in[9];
  const float* w4    = (const float*)d_in[10];
  const float* b4    = (const float*)d_in[11];
  const float* w_ih  = (const float*)d_in[12];
  const float* b_ih  = (const float*)d_in[13];
  const float* w_hh  = (const float*)d_in[14];
  const float* b_hh  = (const float*)d_in[15];
  const float* w_out = (const float*)d_in[16];
  const float* b_out = (const float*)d_in[17];

  char* ws = (char*)d_ws;
  size_t off = 0;
  auto alloc = [&](size_t bytes) -> void* {
    void* p = ws + off;
    off = (off + bytes + 255) & ~(size_t)255;
    return p;
  };

  P_t P;
  P.x = x; P.noise = noise; P.b_cin = b_cin; P.b1 = b1; P.b2 = b2; P.b3 = b3;
  P.w4 = w4; P.b4 = b4; P.b_ih = b_ih; P.b_hh = b_hh; P.w_out = w_out; P.b_out = b_out;
  P.WT1   = (_Float16*)alloc((size_t)HH2 * HH2 * 2);
  P.WT2   = (_Float16*)alloc((size_t)HH2 * HH2 * 2);
  P.WT3   = (_Float16*)alloc((size_t)HH2 * HH2 * 2);
  P.WTih  = (_Float16*)alloc((size_t)GG3 * HSZ * 2);
  P.WThh  = (_Float16*)alloc((size_t)GG3 * HSZ * 2);
  P.WTcin = (_Float16*)alloc((size_t)HSZ * DIN * 2);
  P.FW1   = (_Float16*)alloc((size_t)HH2 * HH2 * 2);
  P.FW2   = (_Float16*)alloc((size_t)HH2 * HH2 * 2);
  P.FW3   = (_Float16*)alloc((size_t)HH2 * HH2 * 2);
  P.FWih  = (_Float16*)alloc((size_t)GG3 * HSZ * 2);
  P.FWhh  = (_Float16*)alloc((size_t)GG3 * HSZ * 2);
  P.CIN   = (_Float16*)alloc((size_t)SLEN * BSZ * HSZ * 2);
  P.Z1    = (_Float16*)alloc((size_t)BSZ * HH2 * 2);
  P.Z2    = (_Float16*)alloc((size_t)BSZ * HH2 * 2);
  P.LOGI  = (float*)alloc((size_t)SLEN * BSZ * 4);
  P.GX    = (float*)alloc((size_t)BSZ * GG3 * 4);
  P.GH    = (float*)alloc((size_t)BSZ * GG3 * 4);
  P.PART  = (float*)alloc((size_t)64 * BSZ * 4);
  P.HGRU  = (float*)alloc((size_t)BSZ * HSZ * 4);
  P.CF    = (float*)alloc((size_t)2 * BSZ * HSZ * 4);
  P.HF    = (float*)alloc((size_t)2 * BSZ * HSZ * 4);
  P.NF    = (float*)alloc((size_t)2 * BSZ * 4);
  P.out   = (float*)d_out;

  transpose_cvt<<<(HH2/32)*(HH2/32), 256, 0, stream>>>(w1, P.WT1, HH2, HH2);
  transpose_cvt<<<(HH2/32)*(HH2/32), 256, 0, stream>>>(w2, P.WT2, HH2, HH2);
  transpose_cvt<<<(HH2/32)*(HH2/32), 256, 0, stream>>>(w3, P.WT3, HH2, HH2);
  transpose_cvt<<<(GG3/32)*(HSZ/32), 256, 0, stream>>>(w_ih, P.WTih, HSZ, GG3);
  transpose_cvt<<<(GG3/32)*(HSZ/32), 256, 0, stream>>>(w_hh, P.WThh, HSZ, GG3);
  transpose_cvt<<<(HSZ/32)*(DIN/32), 256, 0, stream>>>(w_cin, P.WTcin, DIN, HSZ);
  fragpack<<<HH2/16, 512, 0, stream>>>(P.WT1, P.FW1, HH2);
  fragpack<<<HH2/16, 512, 0, stream>>>(P.WT2, P.FW2, HH2);
  fragpack<<<HH2/16, 512, 0, stream>>>(P.WT3, P.FW3, HH2);
  fragpack<<<GG3/16, 512, 0, stream>>>(P.WTih, P.FWih, HSZ);
  fragpack<<<GG3/16, 512, 0, stream>>>(P.WThh, P.FWhh, HSZ);

  cin_kernel<<<1024, 256, 0, stream>>>(P);
  init_kernel<<<512, 256, 0, stream>>>(P);

  for (int t = 0; t < SLEN; ++t) {
    step_k1<<<512, 256, 0, stream>>>(P, t);
    step_k2<<<128, 256, 0, stream>>>(P);
    step_k3<<<128, 256, 0, stream>>>(P, t);
  }
  step_k1<<<512, 256, 0, stream>>>(P, SLEN);   // state(255) + final gx/gh
  final_kernel<<<BSZ, 512, 0, stream>>>(P);
}

// Round 7
// 6442.686 us; speedup vs baseline: 3.2040x; 1.0922x over previous
//
#include <hip/hip_runtime.h>
#include <math.h>

// Problem dims
#define SLEN 256
#define BSZ  128
#define DIN  128
#define HSZ  512
#define HH2  1024
#define GG3  1536
#define OSZ  25
#define SPIN_LIMIT (1 << 22)

typedef _Float16 h8 __attribute__((ext_vector_type(8)));
typedef _Float16 h4v __attribute__((ext_vector_type(4)));
typedef float    f4 __attribute__((ext_vector_type(4)));

struct P_t {
  const float *x, *noise, *b_cin, *b1, *b2, *b3, *w4, *b4, *b_ih, *b_hh, *w_out, *b_out;
  _Float16 *WT1, *WT2, *WT3, *WTih, *WThh, *WTcin;       // row-major [N][K] (setup)
  _Float16 *FW1T, *FW1B, *FW2, *FW3, *FWih, *FWhh;       // fragment-major (hot path)
  _Float16 *CIN, *Z1, *Z2, *HGRU16;
  float *LOGI, *C1, *D1, *CIH, *G;
  float *A1, *AIH, *AHH, *HF, *HGRUF, *NF, *PART;
  int *CNT;
  float *out;
};

__device__ __forceinline__ f4 mfma16(h8 a, h8 b, f4 c) {
  return __builtin_amdgcn_mfma_f32_16x16x32_f16(a, b, c, 0, 0, 0);
}

// ---------------- setup kernels ----------------
__global__ __launch_bounds__(256) void transpose_cvt(const float* __restrict__ src,
    _Float16* __restrict__ dst, int K, int N) {
  __shared__ float tl[32][33];
  int nt = N >> 5;
  int bx = blockIdx.x % nt, by = blockIdx.x / nt;
  int n0 = bx << 5, k0 = by << 5;
  int tx = threadIdx.x & 31, ty = threadIdx.x >> 5;
#pragma unroll
  for (int i = 0; i < 4; ++i) {
    int r = ty + (i << 3);
    tl[r][tx] = src[(size_t)(k0 + r) * N + n0 + tx];
  }
  __syncthreads();
#pragma unroll
  for (int i = 0; i < 4; ++i) {
    int r = ty + (i << 3);
    dst[(size_t)(n0 + r) * K + k0 + tx] = (_Float16)tl[tx][r];
  }
}

// [N][srcK] row-major -> fragment-major over K columns [kOff, kOff+K)
__global__ __launch_bounds__(512) void fragpack2(const _Float16* __restrict__ src,
    _Float16* __restrict__ dst, int srcK, int kOff, int K) {
  int ct = blockIdx.x;
  int chunks = (K / 32) * 64;
  for (int idx = threadIdx.x; idx < chunks; idx += 512) {
    int i = idx >> 6, lane = idx & 63;
    int mlw = lane & 15, qw = lane >> 4;
    *(h8*)(dst + ((size_t)ct * (K / 32) + i) * 512 + (size_t)lane * 8) =
        *(const h8*)(src + ((size_t)ct * 16 + mlw) * srcK + kOff + i * 32 + qw * 8);
  }
}

__global__ __launch_bounds__(256) void cin_kernel(P_t P) {
  int tid = blockIdx.x * blockDim.x + threadIdx.x;
  if (tid < SLEN * BSZ) {
    float u = P.noise[tid];
    P.LOGI[tid] = logf(u) - log1pf(-u);
  }
  int gw = tid >> 6, lane = tid & 63;
  int nw = (gridDim.x * blockDim.x) >> 6;
  int ml = lane & 15, q = lane >> 4;
  const int MT = (SLEN * BSZ) / 16;
  for (int tt = gw; tt < MT * 8; tt += nw) {
    int mt = tt & (MT - 1), nt = tt / MT;
    int m0 = mt * 16, n0 = nt * 64;
    int m = m0 + ml, b = m & 127, s = m >> 7;
    const float* ap = P.x + ((size_t)b * SLEN + s) * DIN + q * 8;
    const _Float16* bp = P.WTcin + (size_t)(n0 + ml) * DIN + q * 8;
    f4 a0 = {0,0,0,0}, a1 = a0, a2 = a0, a3 = a0;
#pragma unroll
    for (int k = 0; k < DIN; k += 32) {
      f4 lo = *(const f4*)(ap + k);
      f4 hi = *(const f4*)(ap + k + 4);
      h8 av;
      av[0] = (_Float16)lo[0]; av[1] = (_Float16)lo[1];
      av[2] = (_Float16)lo[2]; av[3] = (_Float16)lo[3];
      av[4] = (_Float16)hi[0]; av[5] = (_Float16)hi[1];
      av[6] = (_Float16)hi[2]; av[7] = (_Float16)hi[3];
      a0 = mfma16(av, *(const h8*)(bp + k),            a0);
      a1 = mfma16(av, *(const h8*)(bp + 16*DIN + k),   a1);
      a2 = mfma16(av, *(const h8*)(bp + 32*DIN + k),   a2);
      a3 = mfma16(av, *(const h8*)(bp + 48*DIN + k),   a3);
    }
#pragma unroll
    for (int r = 0; r < 4; ++r) {
      int row = m0 + q * 4 + r;
      int c0 = n0 + ml;
      P.CIN[(size_t)row * HSZ + c0     ] = (_Float16)tanhf(a0[r] + P.b_cin[c0]);
      P.CIN[(size_t)row * HSZ + c0 + 16] = (_Float16)tanhf(a1[r] + P.b_cin[c0 + 16]);
      P.CIN[(size_t)row * HSZ + c0 + 32] = (_Float16)tanhf(a2[r] + P.b_cin[c0 + 32]);
      P.CIN[(size_t)row * HSZ + c0 + 48] = (_Float16)tanhf(a3[r] + P.b_cin[c0 + 48]);
    }
  }
}

__global__ __launch_bounds__(256) void init_kernel(P_t P) {
  int idx = blockIdx.x * 256 + threadIdx.x;                 // 65536 threads
  for (int i = idx; i < BSZ * GG3; i += 65536) { P.AIH[i] = 0.f; P.AHH[i] = 0.f; }
  for (int i = idx; i < BSZ * HH2; i += 65536) P.A1[i] = 0.f;
  if (idx < BSZ * HSZ) P.HF[idx] = 0.f;
  if (idx < 2 * BSZ) P.NF[idx] = 0.f;
  if (idx < 128) P.CNT[idx] = 0;
}

// ---------------- bootstrap: Z1(0) and HGRU(0) ----------------
// Z1(0) = relu(cin(0)@W1bot + b1)  (c(-1)=0);  HGRU(0) = gru_cell(0,0) from biases.
__global__ __launch_bounds__(256) void boot_kernel(P_t P) {
  const int tid = threadIdx.x, lane = tid & 63, wv = tid >> 6;
  const int ml = lane & 15, q = lane >> 4;
  const int g = blockIdx.x * 4 + wv;                         // grid 128 -> g<512
  {
    int rt = g & 7, ct = g >> 3, m0 = rt << 4, col = (ct << 4) + ml;
    const _Float16* a0 = P.CIN + (size_t)(m0 + ml) * HSZ + q * 8;   // t=0 rows
    const _Float16* bp = P.FW1B + (size_t)ct * 16 * 512 + (size_t)lane * 8;
    f4 acc = {0.f, 0.f, 0.f, 0.f};
#pragma unroll
    for (int k = 0; k < 16; ++k)
      acc = mfma16(*(const h8*)(a0 + k * 32), *(const h8*)(bp + (size_t)k * 512), acc);
    float bia = P.b1[col];
#pragma unroll
    for (int j = 0; j < 4; ++j)
      P.Z1[(size_t)(m0 + q * 4 + j) * HH2 + col] = (_Float16)fmaxf(acc[j] + bia, 0.f);
  }
  int e = blockIdx.x * 512 + tid;
#pragma unroll
  for (int rep = 0; rep < 2; ++rep, e += 256) {
    int row = e >> 9, cc = e & 511;
    float rg = 1.f / (1.f + expf(-(P.b_ih[cc] + P.b_hh[cc])));
    float zg = 1.f / (1.f + expf(-(P.b_ih[cc + 512] + P.b_hh[cc + 512])));
    float ng = tanhf(P.b_ih[cc + 1024] + rg * P.b_hh[cc + 1024]);
    float v = (1.f - zg) * ng;
    P.HGRUF[(size_t)row * HSZ + cc] = v;
    P.HGRU16[(size_t)row * HSZ + cc] = (_Float16)v;
  }
}

// ---------------- N_A: independent GEMM bundle ----------------
// 768 blocks x 256 thr; tiles: [0,512) z2 | [512,1280) G=HGRU@Whh |
// [1280,1792) C1=cin(t)@W1top | [1792,2560) CIH=cin(t)@Wih | [2560,3072) D1=cin(t+1)@W1bot
__global__ __launch_bounds__(256) void node_a(P_t P, int t) {
  const int tid = threadIdx.x, lane = tid & 63, wv = tid >> 6;
  const int ml = lane & 15, q = lane >> 4;
  const int g = blockIdx.x * 4 + wv;
  f4 acc = {0.f, 0.f, 0.f, 0.f};
  if (g < 512) {                       // z2 (K=1024)
    int rt = g & 7, ct = g >> 3, m0 = rt << 4, col = (ct << 4) + ml;
    const _Float16* a0 = P.Z1 + (size_t)(m0 + ml) * HH2 + q * 8;
    const _Float16* bp = P.FW2 + (size_t)ct * 32 * 512 + (size_t)lane * 8;
#pragma unroll
    for (int k = 0; k < 32; ++k)
      acc = mfma16(*(const h8*)(a0 + k * 32), *(const h8*)(bp + (size_t)k * 512), acc);
    float bia = P.b2[col];
#pragma unroll
    for (int j = 0; j < 4; ++j)
      P.Z2[(size_t)(m0 + q * 4 + j) * HH2 + col] = (_Float16)fmaxf(acc[j] + bia, 0.f);
  } else if (g < 1280) {               // G = HGRU16 @ Whh (no bias)
    int u = g - 512, rt = u & 7, ct = u >> 3, m0 = rt << 4, col = (ct << 4) + ml;
    const _Float16* a0 = P.HGRU16 + (size_t)(m0 + ml) * HSZ + q * 8;
    const _Float16* bp = P.FWhh + (size_t)ct * 16 * 512 + (size_t)lane * 8;
#pragma unroll
    for (int k = 0; k < 16; ++k)
      acc = mfma16(*(const h8*)(a0 + k * 32), *(const h8*)(bp + (size_t)k * 512), acc);
#pragma unroll
    for (int j = 0; j < 4; ++j)
      P.G[(size_t)(m0 + q * 4 + j) * GG3 + col] = acc[j];
  } else if (g < 1792) {               // C1 = cin(t) @ W1top
    int u = g - 1280, rt = u & 7, ct = u >> 3, m0 = rt << 4, col = (ct << 4) + ml;
    const _Float16* a0 = P.CIN + ((size_t)t * BSZ + m0 + ml) * HSZ + q * 8;
    const _Float16* bp = P.FW1T + (size_t)ct * 16 * 512 + (size_t)lane * 8;
#pragma unroll
    for (int k = 0; k < 16; ++k)
      acc = mfma16(*(const h8*)(a0 + k * 32), *(const h8*)(bp + (size_t)k * 512), acc);
#pragma unroll
    for (int j = 0; j < 4; ++j)
      P.C1[(size_t)(m0 + q * 4 + j) * HH2 + col] = acc[j];
  } else if (g < 2560) {               // CIH = cin(t) @ Wih
    int u = g - 1792, rt = u & 7, ct = u >> 3, m0 = rt << 4, col = (ct << 4) + ml;
    const _Float16* a0 = P.CIN + ((size_t)t * BSZ + m0 + ml) * HSZ + q * 8;
    const _Float16* bp = P.FWih + (size_t)ct * 16 * 512 + (size_t)lane * 8;
#pragma unroll
    for (int k = 0; k < 16; ++k)
      acc = mfma16(*(const h8*)(a0 + k * 32), *(const h8*)(bp + (size_t)k * 512), acc);
#pragma unroll
    for (int j = 0; j < 4; ++j)
      P.CIH[(size_t)(m0 + q * 4 + j) * GG3 + col] = acc[j];
  } else {                             // D1 = cin(t+1) @ W1bot
    if (t + 1 < SLEN) {
      int u = g - 2560, rt = u & 7, ct = u >> 3, m0 = rt << 4, col = (ct << 4) + ml;
      const _Float16* a0 = P.CIN + ((size_t)(t + 1) * BSZ + m0 + ml) * HSZ + q * 8;
      const _Float16* bp = P.FW1B + (size_t)ct * 16 * 512 + (size_t)lane * 8;
#pragma unroll
      for (int k = 0; k < 16; ++k)
        acc = mfma16(*(const h8*)(a0 + k * 32), *(const h8*)(bp + (size_t)k * 512), acc);
#pragma unroll
      for (int j = 0; j < 4; ++j)
        P.D1[(size_t)(m0 + q * 4 + j) * HH2 + col] = acc[j];
    }
  }
}

// ---------------- N_B: z3 -> PART (L3 atomics) -> in-kernel tail ----------------
// 128 blocks; block b: rt=b&7 (row block, rows [rt*16,rt*16+16)), sub=b>>3 (0..15).
// z3 tiles: ct = sub*4+wv. PART deposited via relaxed agent atomics (coherent, tiny);
// per-rt counter barrier (16 arrivals; 512 waves total -> all blocks resident; spin
// bounded). Tail: alpha + slice-owned updates of A1/AIH/AHH/h and emission of
// Z1(t+1), gates(t+1) -> HGRU(t+1). Slices are block-private across dispatches.
__global__ __launch_bounds__(256) void node_b(P_t P, int t) {
  const int tid = threadIdx.x, lane = tid & 63, wv = tid >> 6;
  const int ml = lane & 15, q = lane >> 4;
  const int b = blockIdx.x, rt = b & 7, sub = b >> 3;
  const int m0 = rt << 4;
  __shared__ float sAl[16], sNN[16];

  // z3 tile -> PART
  {
    int ct = sub * 4 + wv, col = (ct << 4) + ml;
    const _Float16* a0 = P.Z2 + (size_t)(m0 + ml) * HH2 + q * 8;
    const _Float16* bp = P.FW3 + (size_t)ct * 32 * 512 + (size_t)lane * 8;
    f4 acc = {0.f, 0.f, 0.f, 0.f};
#pragma unroll
    for (int k = 0; k < 32; ++k)
      acc = mfma16(*(const h8*)(a0 + k * 32), *(const h8*)(bp + (size_t)k * 512), acc);
    float bia = P.b3[col], w4v = P.w4[col];
#pragma unroll
    for (int j = 0; j < 4; ++j) {
      float v = fmaxf(acc[j] + bia, 0.f) * w4v;
      v += __shfl_xor(v, 1); v += __shfl_xor(v, 2);
      v += __shfl_xor(v, 4); v += __shfl_xor(v, 8);
      if (ml == 0)
        __hip_atomic_store(&P.PART[(size_t)ct * BSZ + m0 + q * 4 + j], v,
                           __ATOMIC_RELAXED, __HIP_MEMORY_SCOPE_AGENT);
    }
  }
  asm volatile("s_waitcnt vmcnt(0)" ::: "memory");
  __syncthreads();
  if (tid == 0) {
    __hip_atomic_fetch_add(&P.CNT[rt * 16], 1, __ATOMIC_RELAXED, __HIP_MEMORY_SCOPE_AGENT);
    const int target = 16 * (t + 1);
    int tries = 0;
    while (__hip_atomic_load(&P.CNT[rt * 16], __ATOMIC_RELAXED,
                             __HIP_MEMORY_SCOPE_AGENT) < target) {
      if (++tries > SPIN_LIMIT) break;      // graceful: wrong answer, never hang
      __builtin_amdgcn_s_sleep(1);
    }
  }
  __syncthreads();

  // alpha(t), n(t)
  {
    int rl = tid >> 4, sg = tid & 15, row = m0 + rl;
    float v = 0.f;
#pragma unroll
    for (int k2 = 0; k2 < 4; ++k2)
      v += __hip_atomic_load(&P.PART[(size_t)(sg * 4 + k2) * BSZ + row],
                             __ATOMIC_RELAXED, __HIP_MEMORY_SCOPE_AGENT);
    v += __shfl_xor(v, 1); v += __shfl_xor(v, 2);
    v += __shfl_xor(v, 4); v += __shfl_xor(v, 8);
    if (sg == 0) {
      float lg = (v + P.b4[0] + P.LOGI[(size_t)t * BSZ + row]) * 10.0f;
      float al = 1.f / (1.f + expf(-lg));
      float no = P.NF[((t + 1) & 1) * BSZ + row];
      float nn = no * (1.f - al) + 1.f;
      sAl[rl] = al; sNN[rl] = nn;
      if (sub == 0) P.NF[(t & 1) * BSZ + row] = nn;
    }
  }
  __syncthreads();

  // A1 slice (16 rows x 64 cols) + Z1(t+1)
  {
    int rl = tid >> 4, row = m0 + rl;
    int c0 = sub * 64 + (tid & 15) * 4;
    float al = sAl[rl], om = 1.f - al, rin = 1.f / sNN[rl];
    size_t o = (size_t)row * HH2 + c0;
    f4 a = *(f4*)(P.A1 + o);
    f4 c1 = *(const f4*)(P.C1 + o);
#pragma unroll
    for (int j = 0; j < 4; ++j) a[j] = om * a[j] + c1[j];
    *(f4*)(P.A1 + o) = a;
    if (t + 1 < SLEN) {
      f4 d = *(const f4*)(P.D1 + o);
      f4 bb = *(const f4*)(P.b1 + c0);
      h4v zo;
#pragma unroll
      for (int j = 0; j < 4; ++j)
        zo[j] = (_Float16)fmaxf(a[j] * rin + d[j] + bb[j], 0.f);
      *(h4v*)(P.Z1 + o) = zo;
    }
  }

  // AIH/AHH/gates/h/HGRU slice (16 rows x 32 h-cols, gate triples)
  {
    int rl = tid >> 4, row = m0 + rl;
    float al = sAl[rl], om = 1.f - al, rin = 1.f / sNN[rl];
    int cbase = sub * 32 + (tid & 15) * 2;
#pragma unroll
    for (int e = 0; e < 2; ++e) {
      int cc = cbase + e;
      size_t o3 = (size_t)row * GG3 + cc;
      float air = om * P.AIH[o3]        + P.CIH[o3];
      float aiz = om * P.AIH[o3 + 512]  + P.CIH[o3 + 512];
      float ain = om * P.AIH[o3 + 1024] + P.CIH[o3 + 1024];
      P.AIH[o3] = air; P.AIH[o3 + 512] = aiz; P.AIH[o3 + 1024] = ain;
      float ahr = om * P.AHH[o3]        + al * P.G[o3];
      float ahz = om * P.AHH[o3 + 512]  + al * P.G[o3 + 512];
      float ahn = om * P.AHH[o3 + 1024] + al * P.G[o3 + 1024];
      P.AHH[o3] = ahr; P.AHH[o3 + 512] = ahz; P.AHH[o3 + 1024] = ahn;
      float gxr = air * rin + P.b_ih[cc];
      float gxz = aiz * rin + P.b_ih[cc + 512];
      float gxn = ain * rin + P.b_ih[cc + 1024];
      float ghr = ahr + P.b_hh[cc];
      float ghz = ahz + P.b_hh[cc + 512];
      float ghn = ahn + P.b_hh[cc + 1024];
      float rg = 1.f / (1.f + expf(-(gxr + ghr)));
      float zg = 1.f / (1.f + expf(-(gxz + ghz)));
      float ng = tanhf(gxn + rg * ghn);
      size_t oh = (size_t)row * HSZ + cc;
      float hold = P.HF[oh];
      float hgt  = P.HGRUF[oh];             // HGRU(t)
      float hnew = om * hold + al * hgt;    // h(t)
      P.HF[oh] = hnew;
      float hg1 = (1.f - zg) * ng + zg * hnew;   // HGRU(t+1) = gru_cell(c(t),h(t))
      P.HGRUF[oh] = hg1;
      P.HGRU16[oh] = (_Float16)hg1;
    }
  }
}

// ---------------- final: out = HGRU(256) @ w_out + b_out ----------------
__global__ __launch_bounds__(256) void final_out(P_t P) {
  __shared__ float hf[512];
  const int r = blockIdx.x, tid = threadIdx.x;
  const int lane = tid & 63, wv = tid >> 6;
  for (int e = tid; e < 512; e += 256) hf[e] = P.HGRUF[(size_t)r * HSZ + e];
  __syncthreads();
  for (int c = wv; c < OSZ; c += 4) {
    float v = 0.f;
#pragma unroll
    for (int j = 0; j < 8; ++j)
      v += hf[lane + 64 * j] * P.w_out[(size_t)(lane + 64 * j) * OSZ + c];
    for (int off = 32; off > 0; off >>= 1) v += __shfl_xor(v, off);
    if (lane == 0) P.out[r * OSZ + c] = v + P.b_out[c];
  }
}

// ---------------- host ----------------
extern "C" void kernel_launch(void* const* d_in, const int* in_sizes, int n_in,
                              void* d_out, int out_size, void* d_ws, size_t ws_size,
                              hipStream_t stream) {
  const float* x     = (const float*)d_in[0];
  const float* noise = (const float*)d_in[1];
  const float* w_cin = (const float*)d_in[2];
  const float* b_cin = (const float*)d_in[3];
  const float* w1    = (const float*)d_in[4];
  const float* b1    = (const float*)d_in[5];
  const float* w2    = (const float*)d_in[6];
  const float* b2    = (const float*)d_in[7];
  const float* w3    = (const float*)d_in[8];
  const float* b3    = (const float*)d_in[9];
  const float* w4    = (const float*)d_in[10];
  const float* b4    = (const float*)d_in[11];
  const float* w_ih  = (const float*)d_in[12];
  const float* b_ih  = (const float*)d_in[13];
  const float* w_hh  = (const float*)d_in[14];
  const float* b_hh  = (const float*)d_in[15];
  const float* w_out = (const float*)d_in[16];
  const float* b_out = (const float*)d_in[17];

  char* ws = (char*)d_ws;
  size_t off = 0;
  auto alloc = [&](size_t bytes) -> void* {
    void* p = ws + off;
    off = (off + bytes + 255) & ~(size_t)255;
    return p;
  };

  P_t P;
  P.x = x; P.noise = noise; P.b_cin = b_cin; P.b1 = b1; P.b2 = b2; P.b3 = b3;
  P.w4 = w4; P.b4 = b4; P.b_ih = b_ih; P.b_hh = b_hh; P.w_out = w_out; P.b_out = b_out;
  P.WT1    = (_Float16*)alloc((size_t)HH2 * HH2 * 2);
  P.WT2    = (_Float16*)alloc((size_t)HH2 * HH2 * 2);
  P.WT3    = (_Float16*)alloc((size_t)HH2 * HH2 * 2);
  P.WTih   = (_Float16*)alloc((size_t)GG3 * HSZ * 2);
  P.WThh   = (_Float16*)alloc((size_t)GG3 * HSZ * 2);
  P.WTcin  = (_Float16*)alloc((size_t)HSZ * DIN * 2);
  P.FW1T   = (_Float16*)alloc((size_t)HH2 * 512 * 2);
  P.FW1B   = (_Float16*)alloc((size_t)HH2 * 512 * 2);
  P.FW2    = (_Float16*)alloc((size_t)HH2 * HH2 * 2);
  P.FW3    = (_Float16*)alloc((size_t)HH2 * HH2 * 2);
  P.FWih   = (_Float16*)alloc((size_t)GG3 * HSZ * 2);
  P.FWhh   = (_Float16*)alloc((size_t)GG3 * HSZ * 2);
  P.CIN    = (_Float16*)alloc((size_t)SLEN * BSZ * HSZ * 2);
  P.Z1     = (_Float16*)alloc((size_t)BSZ * HH2 * 2);
  P.Z2     = (_Float16*)alloc((size_t)BSZ * HH2 * 2);
  P.HGRU16 = (_Float16*)alloc((size_t)BSZ * HSZ * 2);
  P.LOGI   = (float*)alloc((size_t)SLEN * BSZ * 4);
  P.C1     = (float*)alloc((size_t)BSZ * HH2 * 4);
  P.D1     = (float*)alloc((size_t)BSZ * HH2 * 4);
  P.CIH    = (float*)alloc((size_t)BSZ * GG3 * 4);
  P.G      = (float*)alloc((size_t)BSZ * GG3 * 4);
  P.A1     = (float*)alloc((size_t)BSZ * HH2 * 4);
  P.AIH    = (float*)alloc((size_t)BSZ * GG3 * 4);
  P.AHH    = (float*)alloc((size_t)BSZ * GG3 * 4);
  P.HF     = (float*)alloc((size_t)BSZ * HSZ * 4);
  P.HGRUF  = (float*)alloc((size_t)BSZ * HSZ * 4);
  P.NF     = (float*)alloc((size_t)2 * BSZ * 4);
  P.PART   = (float*)alloc((size_t)64 * BSZ * 4);
  P.CNT    = (int*)alloc(128 * 4);
  P.out    = (float*)d_out;

  transpose_cvt<<<(HH2/32)*(HH2/32), 256, 0, stream>>>(w1, P.WT1, HH2, HH2);
  transpose_cvt<<<(HH2/32)*(HH2/32), 256, 0, stream>>>(w2, P.WT2, HH2, HH2);
  transpose_cvt<<<(HH2/32)*(HH2/32), 256, 0, stream>>>(w3, P.WT3, HH2, HH2);
  transpose_cvt<<<(GG3/32)*(HSZ/32), 256, 0, stream>>>(w_ih, P.WTih, HSZ, GG3);
  transpose_cvt<<<(GG3/32)*(HSZ/32), 256, 0, stream>>>(w_hh, P.WThh, HSZ, GG3);
  transpose_cvt<<<(HSZ/32)*(DIN/32), 256, 0, stream>>>(w_cin, P.WTcin, DIN, HSZ);
  fragpack2<<<HH2/16, 512, 0, stream>>>(P.WT1, P.FW1T, HH2, 0, 512);
  fragpack2<<<HH2/16, 512, 0, stream>>>(P.WT1, P.FW1B, HH2, 512, 512);
  fragpack2<<<HH2/16, 512, 0, stream>>>(P.WT2, P.FW2, HH2, 0, HH2);
  fragpack2<<<HH2/16, 512, 0, stream>>>(P.WT3, P.FW3, HH2, 0, HH2);
  fragpack2<<<GG3/16, 512, 0, stream>>>(P.WTih, P.FWih, HSZ, 0, HSZ);
  fragpack2<<<GG3/16, 512, 0, stream>>>(P.WThh, P.FWhh, HSZ, 0, HSZ);

  cin_kernel<<<1024, 256, 0, stream>>>(P);
  init_kernel<<<256, 256, 0, stream>>>(P);
  boot_kernel<<<128, 256, 0, stream>>>(P);

  for (int t = 0; t < SLEN; ++t) {
    node_a<<<768, 256, 0, stream>>>(P, t);
    node_b<<<128, 256, 0, stream>>>(P, t);
  }
  final_out<<<BSZ, 256, 0, stream>>>(P);
}